// Round 4
// baseline (396.587 us; speedup 1.0000x reference)
//
#include <hip/hip_runtime.h>
#include <math.h>

// x[16][13][512][768] f32 -> out[16][13][3*768]
//   out[..., 0:768]    = sum over seq
//   out[..., 768:1536] = std (ddof=1) over seq
//   out[..., 1536:2304]= max over seq
//
// One fused kernel, 416 blocks = 208 (batch,layer) pairs x 2 hidden-halves.
// Engages all 256 CUs (208-block version left 48 CUs idle). Each block:
// 384 threads = 96 float4-columns x 4 row-groups of 128 rows; row-group
// partials combined through LDS; no cross-block communication needed since
// each block owns a disjoint 384-channel output slice.
#define BL     208           // 16*13
#define SEQ    512
#define HID    768
#define HALFC  96            // float4 columns per hidden-half (384 floats)
#define GROUPS 4
#define ROWS   (SEQ / GROUPS)  // 128 rows per group
#define TPB    (HALFC * GROUPS) // 384 threads, 6 waves

typedef float f4v __attribute__((ext_vector_type(4)));

__global__ __launch_bounds__(TPB) void msm_fused2(
    const float* __restrict__ x, float* __restrict__ out)
{
    // partials from groups 1..3: [stat][group-1][col]
    __shared__ f4v sh[3][GROUPS - 1][HALFC];

    const int bl   = blockIdx.x >> 1;       // 0..207
    const int half = blockIdx.x & 1;        // 0..1
    const int tid  = threadIdx.x;
    const int grp  = tid / HALFC;           // 0..3
    const int col  = tid % HALFC;           // 0..95

    // base of this block's half-row, at row (grp*ROWS)
    const f4v* p = (const f4v*)(x + (size_t)bl * SEQ * HID
                                  + (size_t)grp * ROWS * HID
                                  + (size_t)half * (HID / 2)) + col;

    float sx = 0.f, sy = 0.f, sz = 0.f, sw = 0.f;
    float qx = 0.f, qy = 0.f, qz = 0.f, qw = 0.f;
    float mx = -INFINITY, my = -INFINITY, mz = -INFINITY, mw = -INFINITY;

    #pragma unroll 8
    for (int i = 0; i < ROWS; ++i) {
        f4v v = __builtin_nontemporal_load(p + (size_t)i * (HID / 4));
        sx += v.x; sy += v.y; sz += v.z; sw += v.w;
        qx = fmaf(v.x, v.x, qx); qy = fmaf(v.y, v.y, qy);
        qz = fmaf(v.z, v.z, qz); qw = fmaf(v.w, v.w, qw);
        mx = fmaxf(mx, v.x); my = fmaxf(my, v.y);
        mz = fmaxf(mz, v.z); mw = fmaxf(mw, v.w);
    }

    if (grp > 0) {
        sh[0][grp - 1][col] = (f4v){sx, sy, sz, sw};
        sh[1][grp - 1][col] = (f4v){qx, qy, qz, qw};
        sh[2][grp - 1][col] = (f4v){mx, my, mz, mw};
    }
    __syncthreads();

    if (grp == 0) {
        #pragma unroll
        for (int g = 0; g < GROUPS - 1; ++g) {
            f4v s = sh[0][g][col];
            f4v q = sh[1][g][col];
            f4v m = sh[2][g][col];
            sx += s.x; sy += s.y; sz += s.z; sw += s.w;
            qx += q.x; qy += q.y; qz += q.z; qw += q.w;
            mx = fmaxf(mx, m.x); my = fmaxf(my, m.y);
            mz = fmaxf(mz, m.z); mw = fmaxf(mw, m.w);
        }

        const float invn  = 1.0f / (float)SEQ;
        const float invn1 = 1.0f / ((float)SEQ - 1.0f);

        float vx = fmaxf((qx - sx * sx * invn) * invn1, 0.f);
        float vy = fmaxf((qy - sy * sy * invn) * invn1, 0.f);
        float vz = fmaxf((qz - sz * sz * invn) * invn1, 0.f);
        float vw = fmaxf((qw - sw * sw * invn) * invn1, 0.f);

        // out float4 base for this pair: bl*576; half offset = half*96
        f4v* ob = (f4v*)out + (size_t)bl * 576 + (size_t)half * HALFC;
        ob[col]       = (f4v){sx, sy, sz, sw};
        ob[192 + col] = (f4v){sqrtf(vx), sqrtf(vy), sqrtf(vz), sqrtf(vw)};
        ob[384 + col] = (f4v){mx, my, mz, mw};
    }
}

extern "C" void kernel_launch(void* const* d_in, const int* in_sizes, int n_in,
                              void* d_out, int out_size, void* d_ws, size_t ws_size,
                              hipStream_t stream) {
    const float* x = (const float*)d_in[0];
    float* out = (float*)d_out;
    msm_fused2<<<BL * 2, TPB, 0, stream>>>(x, out);
}